// Round 8
// baseline (122.789 us; speedup 1.0000x reference)
//
#include <hip/hip_runtime.h>
#include <stdint.h>

#define Bb 8
#define Ll 2048
#define Ss 2048
#define Dd 128
#define NSB 8
#define SCHUNK 256
#define NROWS 16384  // Bb*Ll == Bb*Ss
#define SCALE_LOG2E 92.33248261689366f  // 64 * log2(e); also the fixed softmax max

typedef __attribute__((ext_vector_type(8))) short bf16x8;
typedef __attribute__((ext_vector_type(16))) float f32x16;

__device__ __forceinline__ unsigned f2bf_pack(float a, float b) {
  unsigned ua = __float_as_uint(a); ua += 0x7fffu + ((ua >> 16) & 1u);
  unsigned ub = __float_as_uint(b); ub += 0x7fffu + ((ub >> 16) & 1u);
  return (ua >> 16) | (ub & 0xffff0000u);
}

__device__ __forceinline__ unsigned pkbf(float a, float b) {
#if __has_builtin(__builtin_amdgcn_cvt_pk_bf16_f32)
  auto r = __builtin_amdgcn_cvt_pk_bf16_f32(a, b);
  return __builtin_bit_cast(unsigned, r);
#else
  return f2bf_pack(a, b);
#endif
}

__device__ __forceinline__ void gl_lds16(const void* g, void* l) {
  __builtin_amdgcn_global_load_lds(
      (const __attribute__((address_space(1))) unsigned*)g,
      (__attribute__((address_space(3))) unsigned*)l, 16, 0, 0);
}

// Fragment-major layouts, per 32-s block = 8 slots * 1 KB = 8 KB (4096 ushort):
//  Kf slot kt, lane l=(h*32+s): K[s][d=kt*16+h*8+j], j=0..7
//  Vf slot (dblk*2+t2), lane l=(h*32+dloc): V^T[d=dblk*32+dloc][s_perm]
//    s_perm = t2*16 + 4*h + (j&3) + 8*(j>>2)  == S-MFMA C-reg order, so the
//    P B-fragment is just consecutive acc registers (no shuffles).

// ---------------- pre-pass: K/V only (Q-norm folded into attn prologue) ------
extern "C" __global__ __launch_bounds__(256)
void prep_kern(const float* __restrict__ K, const float* __restrict__ V,
               unsigned short* __restrict__ Kf, unsigned short* __restrict__ Vf) {
  __shared__ float Tf[32 * 130];
  __shared__ float Ps[32 * 8];
  __shared__ float Nr[32];
  __shared__ unsigned short Tb[32 * 128];
  const int t = threadIdx.x;
  const int bid = blockIdx.x;
  if (bid < 512) {  // K: 32-row block -> normalize -> frag-major
    const int kb = bid;
    const int b = kb & 7, sw = kb >> 3;
    const int sl = t >> 3, d0 = (t & 7) * 16;
    const float* src = K + ((size_t)(b * Ss + sw * 32 + sl)) * Dd + d0;
    float ss = 0.f;
#pragma unroll
    for (int i = 0; i < 4; ++i) {
      float4 v = *(const float4*)(src + i * 4);
      Tf[sl * 130 + d0 + i * 4 + 0] = v.x;
      Tf[sl * 130 + d0 + i * 4 + 1] = v.y;
      Tf[sl * 130 + d0 + i * 4 + 2] = v.z;
      Tf[sl * 130 + d0 + i * 4 + 3] = v.w;
      ss += v.x * v.x + v.y * v.y + v.z * v.z + v.w * v.w;
    }
    Ps[sl * 8 + (t & 7)] = ss;
    __syncthreads();
    if (t < 32) {
      float s = 0.f;
#pragma unroll
      for (int j = 0; j < 8; ++j) s += Ps[t * 8 + j];
      Nr[t] = 1.0f / fmaxf(sqrtf(s), 1e-12f);
    }
    __syncthreads();
    unsigned short* Ko = Kf + ((size_t)(b * 64 + sw)) * 4096;
#pragma unroll
    for (int p = 0; p < 2; ++p) {
      const int run = p * 256 + t;
      const int lane = run & 63, s = lane & 31, h = lane >> 5;
      const int d = (run >> 6) * 16 + h * 8;
      const float n = Nr[s];
      const float* row = &Tf[s * 130 + d];
      uint4 w;
      w.x = pkbf(row[0] * n, row[1] * n);
      w.y = pkbf(row[2] * n, row[3] * n);
      w.z = pkbf(row[4] * n, row[5] * n);
      w.w = pkbf(row[6] * n, row[7] * n);
      *(uint4*)(Ko + run * 8) = w;
    }
  } else {  // V: 32-row block -> transpose -> j-permuted frag-major
    const int vb = bid - 512;
    const int b = vb & 7, sw = vb >> 3;
    const int sl = t >> 3, d0 = (t & 7) * 16;
    const float* src = V + ((size_t)(b * Ss + sw * 32 + sl)) * Dd + d0;
#pragma unroll
    for (int i = 0; i < 4; ++i) {
      float4 v = *(const float4*)(src + i * 4);
      *(unsigned*)&Tb[sl * 128 + d0 + i * 4]     = pkbf(v.x, v.y);
      *(unsigned*)&Tb[sl * 128 + d0 + i * 4 + 2] = pkbf(v.z, v.w);
    }
    __syncthreads();
    unsigned short* Vo = Vf + ((size_t)(b * 64 + sw)) * 4096;
#pragma unroll
    for (int p = 0; p < 2; ++p) {
      const int run = p * 256 + t;
      const int vslot = run >> 6, lane = run & 63;
      const int dloc = lane & 31, h = lane >> 5;
      const int dblk = vslot >> 1, t2 = vslot & 1;
      const int d = dblk * 32 + dloc;
      unsigned short w[8];
#pragma unroll
      for (int j = 0; j < 8; ++j) {
        const int sloc = t2 * 16 + 4 * h + (j & 3) + 8 * (j >> 2);
        w[j] = Tb[sloc * 128 + d];
      }
      *(uint4*)(Vo + run * 8) = *(uint4*)w;
    }
  }
}

// ---------------- main fused attention: 8-wave blocks, ring-4 pipeline ------
// CLEAN occupancy test vs R6 counters (attn=25us, MfmaUtil 26%, VALUBusy 33%,
// Occ 16% @ 8 waves/CU): keep the verified ring-4 / distance-2 / one counted
// gate per body skeleton EXACTLY (R7's ring-2 regression came from its extra
// post-compute barrier + zero prefetch distance, not from occupancy), and
// double waves/CU by merging two 4-wave blocks: 512 threads, 256 q-rows,
// NSB=8 -> grid 512 = 2 blocks/CU x 8 waves = 16 waves/CU (4/SIMD).
// Staging: wave wv stages K slot wv + V slot wv (2 gl_lds/wave/tile) ->
// gate = `s_waitcnt vmcnt(2); s_barrier` (batch(it) landed, batch(it+1) in
// flight). Ring-4 slot reuse: tile it+2 overwrites the slot consumed at body
// it-2, two gate barriers ago -> no extra barrier. 8 bodies/chunk.
// LDS 64KB x 2 blocks = 128KB; VGPR ~104 <= 128 cap (launch_bounds(512,4)).
extern "C" __global__ __launch_bounds__(512, 4)
void attn_kern(const float* __restrict__ Q,
               const unsigned short* __restrict__ Kf,
               const unsigned short* __restrict__ Vf,
               unsigned short* __restrict__ Op,
               float* __restrict__ Lp) {
  __shared__ unsigned short Kl[4][8 * 512];  // 4-ring of 8-slot (8 KB) K tiles
  __shared__ unsigned short Vl[4][8 * 512];
  const int tid = threadIdx.x, wv = tid >> 6, lane = tid & 63;
  const int lm = lane & 31, h = lane >> 5;
  const int gid = blockIdx.x;
  // gid = qt*64 + b*8 + sb: the 8 qt-sharers of one (b,sb) K/V chunk have gid
  // stride 64 -> same XCD (64%8==0) -> chunk stays in that XCD's L2.
  const int qt = gid >> 6, b = (gid >> 3) & 7, sb = gid & 7;
  const int sblk0 = sb * (SCHUNK / 32);
  const int qrow = qt * 256 + wv * 32 + lm;

  // Q prologue: load own row's fragment chunks (f32), normalize, cvt to bf16.
  // All Q loads are consumed (vmcnt-drained) before the first stage() below,
  // so the gates count only gl_lds staging ops.
  const float* Qr = Q + ((size_t)(b * Ll + qrow)) * Dd;
  float qv[8][8];
  float ss = 0.f;
#pragma unroll
  for (int kt = 0; kt < 8; ++kt) {
    const float* cp = Qr + kt * 16 + h * 8;
    float4 u0 = *(const float4*)cp;
    float4 u1 = *(const float4*)(cp + 4);
    qv[kt][0] = u0.x; qv[kt][1] = u0.y; qv[kt][2] = u0.z; qv[kt][3] = u0.w;
    qv[kt][4] = u1.x; qv[kt][5] = u1.y; qv[kt][6] = u1.z; qv[kt][7] = u1.w;
    ss += u0.x * u0.x + u0.y * u0.y + u0.z * u0.z + u0.w * u0.w +
          u1.x * u1.x + u1.y * u1.y + u1.z * u1.z + u1.w * u1.w;
  }
  ss += __shfl_xor(ss, 32, 64);  // combine the two half-row lanes (h=0,h=1)
  const float qinv = 1.0f / fmaxf(sqrtf(ss), 1e-12f);
  bf16x8 qf[8];
#pragma unroll
  for (int kt = 0; kt < 8; ++kt) {
    uint4 w;
    w.x = pkbf(qv[kt][0] * qinv, qv[kt][1] * qinv);
    w.y = pkbf(qv[kt][2] * qinv, qv[kt][3] * qinv);
    w.z = pkbf(qv[kt][4] * qinv, qv[kt][5] * qinv);
    w.w = pkbf(qv[kt][6] * qinv, qv[kt][7] * qinv);
    qf[kt] = __builtin_bit_cast(bf16x8, w);
  }

  const unsigned short* Kc = Kf + ((size_t)(b * 64 + sblk0)) * 4096;
  const unsigned short* Vc = Vf + ((size_t)(b * 64 + sblk0)) * 4096;

  f32x16 o[4];
#pragma unroll
  for (int i = 0; i < 4; ++i)
#pragma unroll
    for (int r = 0; r < 16; ++r) o[i][r] = 0.f;

  // stage tile t into ring slot r: 2 gl_lds16 per wave (K slot wv, V slot wv)
  auto stage = [&](int t, int r) {
    const unsigned short* kb = Kc + (size_t)t * 4096;
    const unsigned short* vb = Vc + (size_t)t * 4096;
    gl_lds16(kb + wv * 512 + lane * 8, &Kl[r][wv * 512]);
    gl_lds16(vb + wv * 512 + lane * 8, &Vl[r][wv * 512]);
  };
  stage(0, 0);
  stage(1, 1);

  float lrun = 0.f;

#pragma unroll 1
  for (int it = 0; it < 8; ++it) {
    // Gate: batch(it) landed. Outstanding = batches {it, it+1} (2 ops each
    // per wave) -> vmcnt(2). Body 7: only batch 7 outstanding -> vmcnt(0).
    if (it < 7)
      asm volatile("s_waitcnt vmcnt(2)\n\ts_barrier" ::: "memory");
    else
      asm volatile("s_waitcnt vmcnt(0)\n\ts_barrier" ::: "memory");
    const int r = it & 3;
    if (it + 2 < 8) stage(it + 2, (it + 2) & 3);

    // S^T = K · Q^T  (M=s 32, N=m 32, K=d 8x16)
    f32x16 acc;
#pragma unroll
    for (int rr = 0; rr < 16; ++rr) acc[rr] = 0.f;
#pragma unroll
    for (int kt = 0; kt < 8; ++kt) {
      bf16x8 kf = *(const bf16x8*)&Kl[r][kt * 512 + lane * 8];
      acc = __builtin_amdgcn_mfma_f32_32x32x16_bf16(kf, qf[kt], acc, 0, 0, 0);
    }
    // fixed-max softmax; P B-frag = consecutive acc regs (j-permuted Vf)
#pragma unroll
    for (int t2 = 0; t2 < 2; ++t2) {
      float p[8];
#pragma unroll
      for (int j = 0; j < 8; ++j)
        p[j] = __builtin_amdgcn_exp2f(
            __builtin_fmaf(acc[t2 * 8 + j], SCALE_LOG2E, -SCALE_LOG2E));
      lrun += ((p[0] + p[1]) + (p[2] + p[3])) + ((p[4] + p[5]) + (p[6] + p[7]));
      uint4 fr;
      fr.x = pkbf(p[0], p[1]);
      fr.y = pkbf(p[2], p[3]);
      fr.z = pkbf(p[4], p[5]);
      fr.w = pkbf(p[6], p[7]);
      bf16x8 pf = __builtin_bit_cast(bf16x8, fr);
      // O^T += V^T · P^T  (M=d 4x32, N=m 32, K=s 16, s-order pre-permuted)
#pragma unroll
      for (int dblk = 0; dblk < 4; ++dblk) {
        bf16x8 vf = *(const bf16x8*)&Vl[r][(dblk * 2 + t2) * 512 + lane * 8];
        o[dblk] = __builtin_amdgcn_mfma_f32_32x32x16_bf16(vf, pf, o[dblk], 0, 0, 0);
      }
    }
  }

  // epilogue: partial (unnormalized) O bf16 + per-row l (shared fixed max)
  const float lt = lrun + __shfl_xor(lrun, 32, 64);
  unsigned short* Ob = Op + ((size_t)sb * NROWS + b * Ll + qrow) * Dd;
#pragma unroll
  for (int dblk = 0; dblk < 4; ++dblk)
#pragma unroll
    for (int g = 0; g < 4; ++g) {
      uint2 w;
      w.x = pkbf(o[dblk][g * 4 + 0], o[dblk][g * 4 + 1]);
      w.y = pkbf(o[dblk][g * 4 + 2], o[dblk][g * 4 + 3]);
      *(uint2*)(Ob + dblk * 32 + g * 8 + h * 4) = w;  // d = 32*dblk + 8*g + 4*h
    }
  if (h == 0) Lp[(size_t)sb * NROWS + b * Ll + qrow] = lt;
}

// ---------------- combine the NSB S-chunk partials (pure sum: shared max) ---
extern "C" __global__ __launch_bounds__(256)
void comb_kern(const unsigned short* __restrict__ Op,
               const float* __restrict__ Lp, float* __restrict__ Out) {
  const int idx = blockIdx.x * 256 + threadIdx.x;  // one thread per 8 d
  const int row = idx >> 4;
  const int dof = (idx & 15) * 8;
  float den = 0.f;
#pragma unroll
  for (int s = 0; s < NSB; ++s) den += Lp[(size_t)s * NROWS + row];
  float a[8] = {0.f, 0.f, 0.f, 0.f, 0.f, 0.f, 0.f, 0.f};
#pragma unroll
  for (int s = 0; s < NSB; ++s) {
    uint4 v = *(const uint4*)(Op + ((size_t)s * NROWS + row) * Dd + dof);
    a[0] += __uint_as_float(v.x << 16);
    a[1] += __uint_as_float(v.x & 0xffff0000u);
    a[2] += __uint_as_float(v.y << 16);
    a[3] += __uint_as_float(v.y & 0xffff0000u);
    a[4] += __uint_as_float(v.z << 16);
    a[5] += __uint_as_float(v.z & 0xffff0000u);
    a[6] += __uint_as_float(v.w << 16);
    a[7] += __uint_as_float(v.w & 0xffff0000u);
  }
  const float inv = 1.f / den;
  float4 r0; r0.x = a[0] * inv; r0.y = a[1] * inv; r0.z = a[2] * inv; r0.w = a[3] * inv;
  float4 r1; r1.x = a[4] * inv; r1.y = a[5] * inv; r1.z = a[6] * inv; r1.w = a[7] * inv;
  float* op = Out + (size_t)row * Dd + dof;
  *(float4*)op = r0;
  *(float4*)(op + 4) = r1;
}

extern "C" void kernel_launch(void* const* d_in, const int* in_sizes, int n_in,
                              void* d_out, int out_size, void* d_ws, size_t ws_size,
                              hipStream_t stream) {
  const float* Q = (const float*)d_in[0];
  const float* K = (const float*)d_in[1];
  const float* V = (const float*)d_in[2];
  float* Out = (float*)d_out;
  unsigned short* Kf = (unsigned short*)d_ws;                  // 4 MiB (frag-major)
  unsigned short* Vf = Kf + (size_t)NROWS * Dd;                // 4 MiB (frag-major, j-permuted)
  unsigned short* Op = Vf + (size_t)Bb * Dd * Ss;              // 32 MiB (bf16 partials)
  float* Lp = (float*)(Op + (size_t)NSB * NROWS * Dd);         // 512 KiB
  hipLaunchKernelGGL(prep_kern, dim3(1024), dim3(256), 0, stream, K, V, Kf, Vf);
  hipLaunchKernelGGL(attn_kern, dim3(512), dim3(512), 0, stream, Q, Kf, Vf, Op, Lp);
  hipLaunchKernelGGL(comb_kern, dim3(1024), dim3(256), 0, stream, Op, Lp, Out);
}

// Round 9
// 115.091 us; speedup vs baseline: 1.0669x; 1.0669x over previous
//
#include <hip/hip_runtime.h>
#include <stdint.h>

#define Bb 8
#define Ll 2048
#define Ss 2048
#define Dd 128
#define NSB 8
#define SCHUNK 256
#define NROWS 16384  // Bb*Ll == Bb*Ss
#define SCALE_LOG2E 92.33248261689366f  // 64 * log2(e); also the fixed softmax max

typedef __attribute__((ext_vector_type(8))) short bf16x8;
typedef __attribute__((ext_vector_type(16))) float f32x16;

__device__ __forceinline__ unsigned f2bf_pack(float a, float b) {
  unsigned ua = __float_as_uint(a); ua += 0x7fffu + ((ua >> 16) & 1u);
  unsigned ub = __float_as_uint(b); ub += 0x7fffu + ((ub >> 16) & 1u);
  return (ua >> 16) | (ub & 0xffff0000u);
}

__device__ __forceinline__ unsigned pkbf(float a, float b) {
#if __has_builtin(__builtin_amdgcn_cvt_pk_bf16_f32)
  auto r = __builtin_amdgcn_cvt_pk_bf16_f32(a, b);
  return __builtin_bit_cast(unsigned, r);
#else
  return f2bf_pack(a, b);
#endif
}

__device__ __forceinline__ void gl_lds16(const void* g, void* l) {
  __builtin_amdgcn_global_load_lds(
      (const __attribute__((address_space(1))) unsigned*)g,
      (__attribute__((address_space(3))) unsigned*)l, 16, 0, 0);
}

// Fragment-major layouts, per 32-s block = 8 slots * 1 KB = 8 KB (4096 ushort):
//  Kf slot kt, lane l=(h*32+s): K[s][d=kt*16+h*8+j], j=0..7
//  Vf slot (dblk*2+t2), lane l=(h*32+dloc): V^T[d=dblk*32+dloc][s_perm]
//    s_perm = t2*16 + 4*h + (j&3) + 8*(j>>2)  == S-MFMA C-reg order, so the
//    P B-fragment is just consecutive acc registers (no shuffles).

// ---------------- pre-pass: K/V only (Q-norm folded into attn prologue) ------
extern "C" __global__ __launch_bounds__(256)
void prep_kern(const float* __restrict__ K, const float* __restrict__ V,
               unsigned short* __restrict__ Kf, unsigned short* __restrict__ Vf) {
  __shared__ float Tf[32 * 130];
  __shared__ float Ps[32 * 8];
  __shared__ float Nr[32];
  __shared__ unsigned short Tb[32 * 128];
  const int t = threadIdx.x;
  const int bid = blockIdx.x;
  if (bid < 512) {  // K: 32-row block -> normalize -> frag-major
    const int kb = bid;
    const int b = kb & 7, sw = kb >> 3;
    const int sl = t >> 3, d0 = (t & 7) * 16;
    const float* src = K + ((size_t)(b * Ss + sw * 32 + sl)) * Dd + d0;
    float ss = 0.f;
#pragma unroll
    for (int i = 0; i < 4; ++i) {
      float4 v = *(const float4*)(src + i * 4);
      Tf[sl * 130 + d0 + i * 4 + 0] = v.x;
      Tf[sl * 130 + d0 + i * 4 + 1] = v.y;
      Tf[sl * 130 + d0 + i * 4 + 2] = v.z;
      Tf[sl * 130 + d0 + i * 4 + 3] = v.w;
      ss += v.x * v.x + v.y * v.y + v.z * v.z + v.w * v.w;
    }
    Ps[sl * 8 + (t & 7)] = ss;
    __syncthreads();
    if (t < 32) {
      float s = 0.f;
#pragma unroll
      for (int j = 0; j < 8; ++j) s += Ps[t * 8 + j];
      Nr[t] = 1.0f / fmaxf(sqrtf(s), 1e-12f);
    }
    __syncthreads();
    unsigned short* Ko = Kf + ((size_t)(b * 64 + sw)) * 4096;
#pragma unroll
    for (int p = 0; p < 2; ++p) {
      const int run = p * 256 + t;
      const int lane = run & 63, s = lane & 31, h = lane >> 5;
      const int d = (run >> 6) * 16 + h * 8;
      const float n = Nr[s];
      const float* row = &Tf[s * 130 + d];
      uint4 w;
      w.x = pkbf(row[0] * n, row[1] * n);
      w.y = pkbf(row[2] * n, row[3] * n);
      w.z = pkbf(row[4] * n, row[5] * n);
      w.w = pkbf(row[6] * n, row[7] * n);
      *(uint4*)(Ko + run * 8) = w;
    }
  } else {  // V: 32-row block -> transpose -> j-permuted frag-major
    const int vb = bid - 512;
    const int b = vb & 7, sw = vb >> 3;
    const int sl = t >> 3, d0 = (t & 7) * 16;
    const float* src = V + ((size_t)(b * Ss + sw * 32 + sl)) * Dd + d0;
#pragma unroll
    for (int i = 0; i < 4; ++i) {
      float4 v = *(const float4*)(src + i * 4);
      *(unsigned*)&Tb[sl * 128 + d0 + i * 4]     = pkbf(v.x, v.y);
      *(unsigned*)&Tb[sl * 128 + d0 + i * 4 + 2] = pkbf(v.z, v.w);
    }
    __syncthreads();
    unsigned short* Vo = Vf + ((size_t)(b * 64 + sw)) * 4096;
#pragma unroll
    for (int p = 0; p < 2; ++p) {
      const int run = p * 256 + t;
      const int vslot = run >> 6, lane = run & 63;
      const int dloc = lane & 31, h = lane >> 5;
      const int dblk = vslot >> 1, t2 = vslot & 1;
      const int d = dblk * 32 + dloc;
      unsigned short w[8];
#pragma unroll
      for (int j = 0; j < 8; ++j) {
        const int sloc = t2 * 16 + 4 * h + (j & 3) + 8 * (j >> 2);
        w[j] = Tb[sloc * 128 + d];
      }
      *(uint4*)(Vo + run * 8) = *(uint4*)w;
    }
  }
}

// ---------------- main fused attention: ring-3, 3 blocks/CU, 12 waves/CU ----
// R6 counters: attn=25us, MfmaUtil 26%, VALUBusy 33%, Occ 16% @ 8 waves/CU —
// latency-bound, no pipe half-busy. R8 proved the kernel needs ~168 regs/wave
// (104 VGPR + 64 AGPR): cap 128 -> spill (2x slower). So the occupancy ceiling
// is 3 waves/SIMD (512/168). This round reaches it cleanly:
//  - ring-3 (48 KB LDS) -> 3 blocks/CU (144 <= 160 KB). Ring-3 at staging
//    distance 2 is race-free with NO extra barrier: at gate(it)'s barrier all
//    waves have consumed tile it-1, and stage(it+2) targets slot
//    (it+2)%3 == (it-1)%3.
//  - launch_bounds(256,3) -> VGPR cap 170 >= 168 (no spill).
//  - NSB=8 -> grid 1024 >= 768 resident slots.
// Skeleton otherwise identical to the verified R4/R6 structure: one counted
// gate per body (`vmcnt(4)`, final body vmcnt(0)), stage right after gate.
extern "C" __global__ __launch_bounds__(256, 3)
void attn_kern(const float* __restrict__ Q,
               const unsigned short* __restrict__ Kf,
               const unsigned short* __restrict__ Vf,
               unsigned short* __restrict__ Op,
               float* __restrict__ Lp) {
  __shared__ unsigned short Kl[3][8 * 512];  // 3-ring of 8-slot (8 KB) K tiles
  __shared__ unsigned short Vl[3][8 * 512];
  const int tid = threadIdx.x, wv = tid >> 6, lane = tid & 63;
  const int lm = lane & 31, h = lane >> 5;
  const int gid = blockIdx.x;
  // gid = qt*64 + b*8 + sb: the 16 qt-sharers of one (b,sb) K/V chunk have
  // gid stride 64 -> same XCD (64%8==0) -> chunk stays in that XCD's L2.
  const int qt = gid >> 6, b = (gid >> 3) & 7, sb = gid & 7;
  const int sblk0 = sb * (SCHUNK / 32);
  const int qrow = qt * 128 + wv * 32 + lm;

  // Q prologue: load own row's fragment chunks (f32), normalize, cvt to bf16.
  // All Q loads are consumed (vmcnt-drained) before the first stage() below,
  // so the gates count only gl_lds staging ops. qv's registers die before the
  // main loop (peak pressure is the loop body, ~168 incl AGPR).
  const float* Qr = Q + ((size_t)(b * Ll + qrow)) * Dd;
  float qv[8][8];
  float ss = 0.f;
#pragma unroll
  for (int kt = 0; kt < 8; ++kt) {
    const float* cp = Qr + kt * 16 + h * 8;
    float4 u0 = *(const float4*)cp;
    float4 u1 = *(const float4*)(cp + 4);
    qv[kt][0] = u0.x; qv[kt][1] = u0.y; qv[kt][2] = u0.z; qv[kt][3] = u0.w;
    qv[kt][4] = u1.x; qv[kt][5] = u1.y; qv[kt][6] = u1.z; qv[kt][7] = u1.w;
    ss += u0.x * u0.x + u0.y * u0.y + u0.z * u0.z + u0.w * u0.w +
          u1.x * u1.x + u1.y * u1.y + u1.z * u1.z + u1.w * u1.w;
  }
  ss += __shfl_xor(ss, 32, 64);  // combine the two half-row lanes (h=0,h=1)
  const float qinv = 1.0f / fmaxf(sqrtf(ss), 1e-12f);
  bf16x8 qf[8];
#pragma unroll
  for (int kt = 0; kt < 8; ++kt) {
    uint4 w;
    w.x = pkbf(qv[kt][0] * qinv, qv[kt][1] * qinv);
    w.y = pkbf(qv[kt][2] * qinv, qv[kt][3] * qinv);
    w.z = pkbf(qv[kt][4] * qinv, qv[kt][5] * qinv);
    w.w = pkbf(qv[kt][6] * qinv, qv[kt][7] * qinv);
    qf[kt] = __builtin_bit_cast(bf16x8, w);
  }

  const unsigned short* Kc = Kf + ((size_t)(b * 64 + sblk0)) * 4096;
  const unsigned short* Vc = Vf + ((size_t)(b * 64 + sblk0)) * 4096;

  f32x16 o[4];
#pragma unroll
  for (int i = 0; i < 4; ++i)
#pragma unroll
    for (int r = 0; r < 16; ++r) o[i][r] = 0.f;

  // stage tile t into ring slot r: 4 gl_lds16 per wave (2 K + 2 V)
  auto stage = [&](int t, int r) {
    const unsigned short* kb = Kc + (size_t)t * 4096;
    const unsigned short* vb = Vc + (size_t)t * 4096;
#pragma unroll
    for (int i = 0; i < 2; ++i) {
      const int sl = wv * 2 + i;
      gl_lds16(kb + sl * 512 + lane * 8, &Kl[r][sl * 512]);
      gl_lds16(vb + sl * 512 + lane * 8, &Vl[r][sl * 512]);
    }
  };
  stage(0, 0);
  stage(1, 1);

  float lrun = 0.f;
  int r = 0;   // compute slot: it % 3
  int s2 = 2;  // staging slot: (it+2) % 3

#pragma unroll 1
  for (int it = 0; it < 8; ++it) {
    // Gate: batch(it) landed. Outstanding = batches {it, it+1} (4 ops each
    // per wave) -> vmcnt(4). Body 7: only batch 7 outstanding -> vmcnt(0).
    if (it < 7)
      asm volatile("s_waitcnt vmcnt(4)\n\ts_barrier" ::: "memory");
    else
      asm volatile("s_waitcnt vmcnt(0)\n\ts_barrier" ::: "memory");
    if (it + 2 < 8) stage(it + 2, s2);

    // S^T = K · Q^T  (M=s 32, N=m 32, K=d 8x16)
    f32x16 acc;
#pragma unroll
    for (int rr = 0; rr < 16; ++rr) acc[rr] = 0.f;
#pragma unroll
    for (int kt = 0; kt < 8; ++kt) {
      bf16x8 kf = *(const bf16x8*)&Kl[r][kt * 512 + lane * 8];
      acc = __builtin_amdgcn_mfma_f32_32x32x16_bf16(kf, qf[kt], acc, 0, 0, 0);
    }
    // fixed-max softmax; P B-frag = consecutive acc regs (j-permuted Vf)
#pragma unroll
    for (int t2 = 0; t2 < 2; ++t2) {
      float p[8];
#pragma unroll
      for (int j = 0; j < 8; ++j)
        p[j] = __builtin_amdgcn_exp2f(
            __builtin_fmaf(acc[t2 * 8 + j], SCALE_LOG2E, -SCALE_LOG2E));
      lrun += ((p[0] + p[1]) + (p[2] + p[3])) + ((p[4] + p[5]) + (p[6] + p[7]));
      uint4 fr;
      fr.x = pkbf(p[0], p[1]);
      fr.y = pkbf(p[2], p[3]);
      fr.z = pkbf(p[4], p[5]);
      fr.w = pkbf(p[6], p[7]);
      bf16x8 pf = __builtin_bit_cast(bf16x8, fr);
      // O^T += V^T · P^T  (M=d 4x32, N=m 32, K=s 16, s-order pre-permuted)
#pragma unroll
      for (int dblk = 0; dblk < 4; ++dblk) {
        bf16x8 vf = *(const bf16x8*)&Vl[r][(dblk * 2 + t2) * 512 + lane * 8];
        o[dblk] = __builtin_amdgcn_mfma_f32_32x32x16_bf16(vf, pf, o[dblk], 0, 0, 0);
      }
    }

    r = (r == 2) ? 0 : r + 1;
    s2 = (s2 == 2) ? 0 : s2 + 1;
  }

  // epilogue: partial (unnormalized) O bf16 + per-row l (shared fixed max)
  const float lt = lrun + __shfl_xor(lrun, 32, 64);
  unsigned short* Ob = Op + ((size_t)sb * NROWS + b * Ll + qrow) * Dd;
#pragma unroll
  for (int dblk = 0; dblk < 4; ++dblk)
#pragma unroll
    for (int g = 0; g < 4; ++g) {
      uint2 w;
      w.x = pkbf(o[dblk][g * 4 + 0], o[dblk][g * 4 + 1]);
      w.y = pkbf(o[dblk][g * 4 + 2], o[dblk][g * 4 + 3]);
      *(uint2*)(Ob + dblk * 32 + g * 8 + h * 4) = w;  // d = 32*dblk + 8*g + 4*h
    }
  if (h == 0) Lp[(size_t)sb * NROWS + b * Ll + qrow] = lt;
}

// ---------------- combine the NSB S-chunk partials (pure sum: shared max) ---
extern "C" __global__ __launch_bounds__(256)
void comb_kern(const unsigned short* __restrict__ Op,
               const float* __restrict__ Lp, float* __restrict__ Out) {
  const int idx = blockIdx.x * 256 + threadIdx.x;  // one thread per 8 d
  const int row = idx >> 4;
  const int dof = (idx & 15) * 8;
  float den = 0.f;
#pragma unroll
  for (int s = 0; s < NSB; ++s) den += Lp[(size_t)s * NROWS + row];
  float a[8] = {0.f, 0.f, 0.f, 0.f, 0.f, 0.f, 0.f, 0.f};
#pragma unroll
  for (int s = 0; s < NSB; ++s) {
    uint4 v = *(const uint4*)(Op + ((size_t)s * NROWS + row) * Dd + dof);
    a[0] += __uint_as_float(v.x << 16);
    a[1] += __uint_as_float(v.x & 0xffff0000u);
    a[2] += __uint_as_float(v.y << 16);
    a[3] += __uint_as_float(v.y & 0xffff0000u);
    a[4] += __uint_as_float(v.z << 16);
    a[5] += __uint_as_float(v.z & 0xffff0000u);
    a[6] += __uint_as_float(v.w << 16);
    a[7] += __uint_as_float(v.w & 0xffff0000u);
  }
  const float inv = 1.f / den;
  float4 r0; r0.x = a[0] * inv; r0.y = a[1] * inv; r0.z = a[2] * inv; r0.w = a[3] * inv;
  float4 r1; r1.x = a[4] * inv; r1.y = a[5] * inv; r1.z = a[6] * inv; r1.w = a[7] * inv;
  float* op = Out + (size_t)row * Dd + dof;
  *(float4*)op = r0;
  *(float4*)(op + 4) = r1;
}

extern "C" void kernel_launch(void* const* d_in, const int* in_sizes, int n_in,
                              void* d_out, int out_size, void* d_ws, size_t ws_size,
                              hipStream_t stream) {
  const float* Q = (const float*)d_in[0];
  const float* K = (const float*)d_in[1];
  const float* V = (const float*)d_in[2];
  float* Out = (float*)d_out;
  unsigned short* Kf = (unsigned short*)d_ws;                  // 4 MiB (frag-major)
  unsigned short* Vf = Kf + (size_t)NROWS * Dd;                // 4 MiB (frag-major, j-permuted)
  unsigned short* Op = Vf + (size_t)Bb * Dd * Ss;              // 32 MiB (bf16 partials)
  float* Lp = (float*)(Op + (size_t)NSB * NROWS * Dd);         // 512 KiB
  hipLaunchKernelGGL(prep_kern, dim3(1024), dim3(256), 0, stream, K, V, Kf, Vf);
  hipLaunchKernelGGL(attn_kern, dim3(1024), dim3(256), 0, stream, Q, Kf, Vf, Op, Lp);
  hipLaunchKernelGGL(comb_kern, dim3(1024), dim3(256), 0, stream, Op, Lp, Out);
}

// Round 10
// 106.717 us; speedup vs baseline: 1.1506x; 1.0785x over previous
//
#include <hip/hip_runtime.h>
#include <stdint.h>

#define Bb 8
#define Ll 2048
#define Ss 2048
#define Dd 128
#define NSB 4
#define SCHUNK 512
#define NROWS 16384  // Bb*Ll == Bb*Ss
#define SCALE_LOG2E 92.33248261689366f  // 64 * log2(e); also the fixed softmax max

typedef __attribute__((ext_vector_type(8))) short bf16x8;
typedef __attribute__((ext_vector_type(16))) float f32x16;

__device__ __forceinline__ unsigned f2bf_pack(float a, float b) {
  unsigned ua = __float_as_uint(a); ua += 0x7fffu + ((ua >> 16) & 1u);
  unsigned ub = __float_as_uint(b); ub += 0x7fffu + ((ub >> 16) & 1u);
  return (ua >> 16) | (ub & 0xffff0000u);
}

__device__ __forceinline__ unsigned pkbf(float a, float b) {
#if __has_builtin(__builtin_amdgcn_cvt_pk_bf16_f32)
  auto r = __builtin_amdgcn_cvt_pk_bf16_f32(a, b);
  return __builtin_bit_cast(unsigned, r);
#else
  return f2bf_pack(a, b);
#endif
}

__device__ __forceinline__ void gl_lds16(const void* g, void* l) {
  __builtin_amdgcn_global_load_lds(
      (const __attribute__((address_space(1))) unsigned*)g,
      (__attribute__((address_space(3))) unsigned*)l, 16, 0, 0);
}

// Fragment-major layouts, per 32-s block = 8 slots * 1 KB = 8 KB (4096 ushort):
//  Kf slot kt, lane l=(h*32+s): K[s][d=kt*16+h*8+j], j=0..7
//  Vf slot (dblk*2+t2), lane l=(h*32+dloc): V^T[d=dblk*32+dloc][s_perm]
//    s_perm = t2*16 + 4*h + (j&3) + 8*(j>>2)  == S-MFMA C-reg order, so the
//    P B-fragment is just consecutive acc registers (no shuffles).

// ---------------- pre-pass: K/V only (Q-norm folded into attn prologue) ------
extern "C" __global__ __launch_bounds__(256)
void prep_kern(const float* __restrict__ K, const float* __restrict__ V,
               unsigned short* __restrict__ Kf, unsigned short* __restrict__ Vf) {
  __shared__ float Tf[32 * 130];
  __shared__ float Ps[32 * 8];
  __shared__ float Nr[32];
  __shared__ unsigned short Tb[32 * 128];
  const int t = threadIdx.x;
  const int bid = blockIdx.x;
  if (bid < 512) {  // K: 32-row block -> normalize -> frag-major
    const int kb = bid;
    const int b = kb & 7, sw = kb >> 3;
    const int sl = t >> 3, d0 = (t & 7) * 16;
    const float* src = K + ((size_t)(b * Ss + sw * 32 + sl)) * Dd + d0;
    float ss = 0.f;
#pragma unroll
    for (int i = 0; i < 4; ++i) {
      float4 v = *(const float4*)(src + i * 4);
      Tf[sl * 130 + d0 + i * 4 + 0] = v.x;
      Tf[sl * 130 + d0 + i * 4 + 1] = v.y;
      Tf[sl * 130 + d0 + i * 4 + 2] = v.z;
      Tf[sl * 130 + d0 + i * 4 + 3] = v.w;
      ss += v.x * v.x + v.y * v.y + v.z * v.z + v.w * v.w;
    }
    Ps[sl * 8 + (t & 7)] = ss;
    __syncthreads();
    if (t < 32) {
      float s = 0.f;
#pragma unroll
      for (int j = 0; j < 8; ++j) s += Ps[t * 8 + j];
      Nr[t] = 1.0f / fmaxf(sqrtf(s), 1e-12f);
    }
    __syncthreads();
    unsigned short* Ko = Kf + ((size_t)(b * 64 + sw)) * 4096;
#pragma unroll
    for (int p = 0; p < 2; ++p) {
      const int run = p * 256 + t;
      const int lane = run & 63, s = lane & 31, h = lane >> 5;
      const int d = (run >> 6) * 16 + h * 8;
      const float n = Nr[s];
      const float* row = &Tf[s * 130 + d];
      uint4 w;
      w.x = pkbf(row[0] * n, row[1] * n);
      w.y = pkbf(row[2] * n, row[3] * n);
      w.z = pkbf(row[4] * n, row[5] * n);
      w.w = pkbf(row[6] * n, row[7] * n);
      *(uint4*)(Ko + run * 8) = w;
    }
  } else {  // V: 32-row block -> transpose -> j-permuted frag-major
    const int vb = bid - 512;
    const int b = vb & 7, sw = vb >> 3;
    const int sl = t >> 3, d0 = (t & 7) * 16;
    const float* src = V + ((size_t)(b * Ss + sw * 32 + sl)) * Dd + d0;
#pragma unroll
    for (int i = 0; i < 4; ++i) {
      float4 v = *(const float4*)(src + i * 4);
      *(unsigned*)&Tb[sl * 128 + d0 + i * 4]     = pkbf(v.x, v.y);
      *(unsigned*)&Tb[sl * 128 + d0 + i * 4 + 2] = pkbf(v.z, v.w);
    }
    __syncthreads();
    unsigned short* Vo = Vf + ((size_t)(b * 64 + sw)) * 4096;
#pragma unroll
    for (int p = 0; p < 2; ++p) {
      const int run = p * 256 + t;
      const int vslot = run >> 6, lane = run & 63;
      const int dloc = lane & 31, h = lane >> 5;
      const int dblk = vslot >> 1, t2 = vslot & 1;
      const int d = dblk * 32 + dloc;
      unsigned short w[8];
#pragma unroll
      for (int j = 0; j < 8; ++j) {
        const int sloc = t2 * 16 + 4 * h + (j & 3) + 8 * (j >> 2);
        w[j] = Tb[sloc * 128 + d];
      }
      *(uint4*)(Vo + run * 8) = *(uint4*)w;
    }
  }
}

// ---------------- main fused attention: vmcnt-gated ring + T15 pipeline ----
// grid 512: gid = qt*32 + b*4 + sb; 4 waves, 32 q-rows each; SCHUNK=512,
// 16 tiles of 32-s. 4-deep LDS ring (64 KB), staged at distance 2; per-body
// gate = `s_waitcnt vmcnt(4); s_barrier` (never drains in-flight prefetch).
// Best-measured configuration of the session (R4: 106.0 us). Occupancy
// (8/12/16 waves/CU), ring depth (2/3/4), T5/split-acc, and q64 variants all
// measured neutral-or-worse (rounds 1-9); the timed region is dominated by
// the harness's 256 MiB workspace re-poison fills (~45 us each, themselves
// HBM-roofline-bound), under which most of this kernel's ~25 us is hidden.
extern "C" __global__ __launch_bounds__(256, 2)
void attn_kern(const float* __restrict__ Q,
               const unsigned short* __restrict__ Kf,
               const unsigned short* __restrict__ Vf,
               unsigned short* __restrict__ Op,
               float* __restrict__ Lp) {
  __shared__ unsigned short Kl[4][8 * 512];  // 4-ring of 8-slot (8 KB) K tiles
  __shared__ unsigned short Vl[4][8 * 512];
  const int tid = threadIdx.x, wv = tid >> 6, lane = tid & 63;
  const int lm = lane & 31, h = lane >> 5;
  const int gid = blockIdx.x;
  const int qt = gid >> 5, b = (gid >> 2) & 7, sb = gid & 3;
  const int sblk0 = sb * (SCHUNK / 32);
  const int qrow = qt * 128 + wv * 32 + lm;

  // Q prologue: load own row's fragment chunks (f32), normalize, cvt to bf16.
  // All Q loads are consumed (vmcnt-drained) before the first stage() below,
  // so the gate's vmcnt(4) counts only gl_lds staging ops.
  const float* Qr = Q + ((size_t)(b * Ll + qrow)) * Dd;
  float qv[8][8];
  float ss = 0.f;
#pragma unroll
  for (int kt = 0; kt < 8; ++kt) {
    const float* cp = Qr + kt * 16 + h * 8;
    float4 u0 = *(const float4*)cp;
    float4 u1 = *(const float4*)(cp + 4);
    qv[kt][0] = u0.x; qv[kt][1] = u0.y; qv[kt][2] = u0.z; qv[kt][3] = u0.w;
    qv[kt][4] = u1.x; qv[kt][5] = u1.y; qv[kt][6] = u1.z; qv[kt][7] = u1.w;
    ss += u0.x * u0.x + u0.y * u0.y + u0.z * u0.z + u0.w * u0.w +
          u1.x * u1.x + u1.y * u1.y + u1.z * u1.z + u1.w * u1.w;
  }
  ss += __shfl_xor(ss, 32, 64);  // combine the two half-row lanes (h=0,h=1)
  const float qinv = 1.0f / fmaxf(sqrtf(ss), 1e-12f);
  bf16x8 qf[8];
#pragma unroll
  for (int kt = 0; kt < 8; ++kt) {
    uint4 w;
    w.x = pkbf(qv[kt][0] * qinv, qv[kt][1] * qinv);
    w.y = pkbf(qv[kt][2] * qinv, qv[kt][3] * qinv);
    w.z = pkbf(qv[kt][4] * qinv, qv[kt][5] * qinv);
    w.w = pkbf(qv[kt][6] * qinv, qv[kt][7] * qinv);
    qf[kt] = __builtin_bit_cast(bf16x8, w);
  }

  const unsigned short* Kc = Kf + ((size_t)(b * 64 + sblk0)) * 4096;
  const unsigned short* Vc = Vf + ((size_t)(b * 64 + sblk0)) * 4096;

  f32x16 o[4];
#pragma unroll
  for (int i = 0; i < 4; ++i)
#pragma unroll
    for (int r = 0; r < 16; ++r) o[i][r] = 0.f;

  // stage tile t into ring slot r: 4 gl_lds16 per wave (2 K + 2 V)
  auto stage = [&](int t, int r) {
    const unsigned short* kb = Kc + (size_t)t * 4096;
    const unsigned short* vb = Vc + (size_t)t * 4096;
#pragma unroll
    for (int i = 0; i < 2; ++i) {
      const int sl = wv * 2 + i;
      gl_lds16(kb + sl * 512 + lane * 8, &Kl[r][sl * 512]);
      gl_lds16(vb + sl * 512 + lane * 8, &Vl[r][sl * 512]);
    }
  };

  float lrun = 0.f;
  f32x16 accA, accB;

  // QK(tile in ring slot `slot`) -> a
  auto qk = [&](f32x16& a, int slot) {
#pragma unroll
    for (int rr = 0; rr < 16; ++rr) a[rr] = 0.f;
#pragma unroll
    for (int kt = 0; kt < 8; ++kt) {
      bf16x8 kf = *(const bf16x8*)&Kl[slot][kt * 512 + lane * 8];
      a = __builtin_amdgcn_mfma_f32_32x32x16_bf16(kf, qf[kt], a, 0, 0, 0);
    }
  };
  // softmax + PV for the tile whose scores are in `a`, V in ring slot `slot`
  auto smpv = [&](const f32x16& a, int slot) {
#pragma unroll
    for (int t2 = 0; t2 < 2; ++t2) {
      float p[8];
#pragma unroll
      for (int j = 0; j < 8; ++j)
        p[j] = __builtin_amdgcn_exp2f(
            __builtin_fmaf(a[t2 * 8 + j], SCALE_LOG2E, -SCALE_LOG2E));
      lrun += ((p[0] + p[1]) + (p[2] + p[3])) + ((p[4] + p[5]) + (p[6] + p[7]));
      uint4 fr;
      fr.x = pkbf(p[0], p[1]);
      fr.y = pkbf(p[2], p[3]);
      fr.z = pkbf(p[4], p[5]);
      fr.w = pkbf(p[6], p[7]);
      bf16x8 pf = __builtin_bit_cast(bf16x8, fr);
#pragma unroll
      for (int dblk = 0; dblk < 4; ++dblk) {
        bf16x8 vf = *(const bf16x8*)&Vl[slot][(dblk * 2 + t2) * 512 + lane * 8];
        o[dblk] = __builtin_amdgcn_mfma_f32_32x32x16_bf16(vf, pf, o[dblk], 0, 0, 0);
      }
    }
  };

  stage(0, 0);
  stage(1, 1);

  // body 0: gate tile 0 (outstanding = batches 0,1 -> vmcnt(4) drains batch 0)
  asm volatile("s_waitcnt vmcnt(4)\n\ts_barrier" ::: "memory");
  stage(2, 2);
  qk(accA, 0);

  // bodies 1..14: gate(tile it) -> stage(it+2) -> QK(it) || SM+PV(it-1).
  // Invariant at body it's gate: outstanding = batches {it, it+1} (8 per-wave
  // ops) -> vmcnt(4) completes batch it, leaves it+1 in flight.
#pragma unroll 1
  for (int i2 = 0; i2 < 7; ++i2) {
    const int itO = 2 * i2 + 1;  // odd body: QK->accB, SM/PV from accA
    asm volatile("s_waitcnt vmcnt(4)\n\ts_barrier" ::: "memory");
    stage(itO + 2, (itO + 2) & 3);
    qk(accB, itO & 3);
    smpv(accA, (itO - 1) & 3);
    const int itE = itO + 1;     // even body: QK->accA, SM/PV from accB
    asm volatile("s_waitcnt vmcnt(4)\n\ts_barrier" ::: "memory");
    if (itE + 2 <= 15) stage(itE + 2, (itE + 2) & 3);
    qk(accA, itE & 3);
    smpv(accB, (itE - 1) & 3);
  }

  // body 15: only batch 15 outstanding -> full drain
  asm volatile("s_waitcnt vmcnt(0)\n\ts_barrier" ::: "memory");
  qk(accB, 15 & 3);
  smpv(accA, 14 & 3);
  // tail body 16: finish tile 15
  smpv(accB, 15 & 3);

  // epilogue: partial (unnormalized) O bf16 + per-row l (shared fixed max)
  const float lt = lrun + __shfl_xor(lrun, 32, 64);
  unsigned short* Ob = Op + ((size_t)sb * NROWS + b * Ll + qrow) * Dd;
#pragma unroll
  for (int dblk = 0; dblk < 4; ++dblk)
#pragma unroll
    for (int g = 0; g < 4; ++g) {
      uint2 w;
      w.x = pkbf(o[dblk][g * 4 + 0], o[dblk][g * 4 + 1]);
      w.y = pkbf(o[dblk][g * 4 + 2], o[dblk][g * 4 + 3]);
      *(uint2*)(Ob + dblk * 32 + g * 8 + h * 4) = w;  // d = 32*dblk + 8*g + 4*h
    }
  if (h == 0) Lp[sb * NROWS + b * Ll + qrow] = lt;
}

// ---------------- combine the NSB S-chunk partials (pure sum: shared max) ---
extern "C" __global__ __launch_bounds__(256)
void comb_kern(const unsigned short* __restrict__ Op,
               const float* __restrict__ Lp, float* __restrict__ Out) {
  const int idx = blockIdx.x * 256 + threadIdx.x;  // one thread per 8 d
  const int row = idx >> 4;
  const int dof = (idx & 15) * 8;
  float den = 0.f;
#pragma unroll
  for (int s = 0; s < NSB; ++s) den += Lp[s * NROWS + row];
  float a[8] = {0.f, 0.f, 0.f, 0.f, 0.f, 0.f, 0.f, 0.f};
#pragma unroll
  for (int s = 0; s < NSB; ++s) {
    uint4 v = *(const uint4*)(Op + ((size_t)s * NROWS + row) * Dd + dof);
    a[0] += __uint_as_float(v.x << 16);
    a[1] += __uint_as_float(v.x & 0xffff0000u);
    a[2] += __uint_as_float(v.y << 16);
    a[3] += __uint_as_float(v.y & 0xffff0000u);
    a[4] += __uint_as_float(v.z << 16);
    a[5] += __uint_as_float(v.z & 0xffff0000u);
    a[6] += __uint_as_float(v.w << 16);
    a[7] += __uint_as_float(v.w & 0xffff0000u);
  }
  const float inv = 1.f / den;
  float4 r0; r0.x = a[0] * inv; r0.y = a[1] * inv; r0.z = a[2] * inv; r0.w = a[3] * inv;
  float4 r1; r1.x = a[4] * inv; r1.y = a[5] * inv; r1.z = a[6] * inv; r1.w = a[7] * inv;
  float* op = Out + (size_t)row * Dd + dof;
  *(float4*)op = r0;
  *(float4*)(op + 4) = r1;
}

extern "C" void kernel_launch(void* const* d_in, const int* in_sizes, int n_in,
                              void* d_out, int out_size, void* d_ws, size_t ws_size,
                              hipStream_t stream) {
  const float* Q = (const float*)d_in[0];
  const float* K = (const float*)d_in[1];
  const float* V = (const float*)d_in[2];
  float* Out = (float*)d_out;
  unsigned short* Kf = (unsigned short*)d_ws;                  // 4 MiB (frag-major)
  unsigned short* Vf = Kf + (size_t)NROWS * Dd;                // 4 MiB (frag-major, j-permuted)
  unsigned short* Op = Vf + (size_t)Bb * Dd * Ss;              // 16 MiB (bf16 partials)
  float* Lp = (float*)(Op + (size_t)NSB * NROWS * Dd);         // 256 KiB
  hipLaunchKernelGGL(prep_kern, dim3(1024), dim3(256), 0, stream, K, V, Kf, Vf);
  hipLaunchKernelGGL(attn_kern, dim3(512), dim3(256), 0, stream, Q, Kf, Vf, Op, Lp);
  hipLaunchKernelGGL(comb_kern, dim3(1024), dim3(256), 0, stream, Op, Lp, Out);
}